// Round 1
// baseline (530.566 us; speedup 1.0000x reference)
//
#include <hip/hip_runtime.h>
#include <math.h>

#define NREG 90
#define NN 91
#define STR 92            // padded LDS row stride (floats), multiple of 4 -> 16B-aligned rows
#define NPAIR 4005
#define H1 256
#define H2 256
#define F1 128

__global__ __launch_bounds__(256, 4)
void gcn_fused(const float* __restrict__ coh,   // [B, 4005]
               const float* __restrict__ W1,    // [256, 91]
               const float* __restrict__ W2,    // [256, 256]
               const float* __restrict__ Wo1,   // [128, 256]
               const float* __restrict__ bo1,   // [128]
               const float* __restrict__ Wo2,   // [2, 128]
               const float* __restrict__ bo2,   // [2]
               float* __restrict__ out)         // [B, 2]
{
    __shared__ __align__(16) float A[NN * STR];   // 33488 B
    __shared__ float dinv[NN];
    __shared__ __align__(16) float svec[H1];
    __shared__ __align__(16) float pooled[H2];
    __shared__ __align__(16) float fc1[F1];

    const int b = blockIdx.x;
    const int t = threadIdx.x;
    const float* cb = coh + (size_t)b * NPAIR;

    // ---- 1) zero A ----
    for (int i = t; i < NN * STR; i += 256) A[i] = 0.0f;
    __syncthreads();

    // ---- 2) scatter coh into strict upper triangle + mirror ----
    // row offsets o(i) = i*(2N-1-i)/2, N=90 -> o(i) = i*(179-i)/2
    for (int m = t; m < NPAIR; m += 256) {
        float disc = 32041.0f - 8.0f * (float)m;        // (179)^2 - 8m, exact square at row starts
        int i = (int)floorf((179.0f - sqrtf(disc)) * 0.5f);
        if (i < 0) i = 0;
        while (i > 0 && m < i * (179 - i) / 2) --i;
        while (m >= (i + 1) * (178 - i) / 2) ++i;
        int oi = i * (179 - i) / 2;
        int j = i + 1 + (m - oi);
        float v = cb[m];
        A[i * STR + j] = v;
        A[j * STR + i] = v;
    }
    __syncthreads();

    // ---- 3) supernode links + identity ----
    if (t < NN) {
        A[t * STR + t] = 1.0f;                  // diagonal (strict-triangle scatter left it 0)
        if (t < NREG) {
            A[NREG * STR + t] = 1.0f;           // supernode row
            A[t * STR + NREG] = 1.0f;           // supernode col
        }
    }
    __syncthreads();

    // ---- 4) degree^-1/2 ----
    if (t < NN) {
        float sum = 0.0f;
        const float* row = &A[t * STR];
        for (int j = 0; j < NN; ++j) sum += row[j];
        dinv[t] = 1.0f / sqrtf(sum);
    }
    __syncthreads();

    // ---- 5) A_hat = dinv[i] * A * dinv[j], in place ----
    for (int m = t; m < NN * NN; m += 256) {
        int i = m / NN;
        int j = m - i * NN;
        A[i * STR + j] *= dinv[i] * dinv[j];
    }
    __syncthreads();

    // ---- 6) W1 row -> registers (thread t owns channel h = t) ----
    float w[NN];
    {
        const float* w1r = W1 + t * NN;
        #pragma unroll
        for (int k = 0; k < NN; ++k) w[k] = w1r[k];
    }

    // ---- 7) main loop: s[h] = sum_j arow[j] * relu(dot(Ahat[j,:], w)) ----
    float acc = 0.0f;
    for (int j = 0; j < NN; ++j) {
        const float4* Aj4 = (const float4*)(&A[j * STR]);   // row j, 16B aligned (368B stride)
        float y0 = 0.0f, y1 = 0.0f, y2 = 0.0f, y3 = 0.0f;
        #pragma unroll
        for (int q = 0; q < 22; ++q) {                      // k = 0..87
            float4 a = Aj4[q];
            y0 = fmaf(a.x, w[4 * q + 0], y0);
            y1 = fmaf(a.y, w[4 * q + 1], y1);
            y2 = fmaf(a.z, w[4 * q + 2], y2);
            y3 = fmaf(a.w, w[4 * q + 3], y3);
        }
        y0 = fmaf(A[j * STR + 88], w[88], y0);
        y1 = fmaf(A[j * STR + 89], w[89], y1);
        y2 = fmaf(A[j * STR + 90], w[90], y2);
        float y = (y0 + y1) + (y2 + y3);
        acc = fmaf(fmaxf(y, 0.0f), A[NREG * STR + j], acc);
    }

    svec[t] = acc;
    __syncthreads();

    // ---- 8) pooled[g] = sum_h W2[g,h] * s[h] ----
    {
        const float* w2r = W2 + t * H1;                     // row t, 1KB-aligned
        float p0 = 0.0f, p1 = 0.0f, p2 = 0.0f, p3 = 0.0f;
        #pragma unroll 8
        for (int q = 0; q < H1 / 4; ++q) {
            float4 sv = ((const float4*)svec)[q];
            float4 wv = ((const float4*)w2r)[q];
            p0 = fmaf(sv.x, wv.x, p0);
            p1 = fmaf(sv.y, wv.y, p1);
            p2 = fmaf(sv.z, wv.z, p2);
            p3 = fmaf(sv.w, wv.w, p3);
        }
        pooled[t] = (p0 + p1) + (p2 + p3);
    }
    __syncthreads();

    // ---- 9) fc1 = relu(Wo1 @ pooled + bo1) ----
    if (t < F1) {
        const float* wo1r = Wo1 + t * H2;                   // row t, 1KB-aligned
        float p0 = bo1[t], p1 = 0.0f, p2 = 0.0f, p3 = 0.0f;
        #pragma unroll 8
        for (int q = 0; q < H2 / 4; ++q) {
            float4 pv = ((const float4*)pooled)[q];
            float4 wv = ((const float4*)wo1r)[q];
            p0 = fmaf(pv.x, wv.x, p0);
            p1 = fmaf(pv.y, wv.y, p1);
            p2 = fmaf(pv.z, wv.z, p2);
            p3 = fmaf(pv.w, wv.w, p3);
        }
        fc1[t] = fmaxf((p0 + p1) + (p2 + p3), 0.0f);
    }
    __syncthreads();

    // ---- 10) out = Wo2 @ fc1 + bo2 ----
    if (t < 2) {
        const float* wo2r = Wo2 + t * F1;
        float p = bo2[t];
        for (int f = 0; f < F1; ++f) p = fmaf(wo2r[f], fc1[f], p);
        out[(size_t)b * 2 + t] = p;
    }
}

extern "C" void kernel_launch(void* const* d_in, const int* in_sizes, int n_in,
                              void* d_out, int out_size, void* d_ws, size_t ws_size,
                              hipStream_t stream) {
    const float* coh = (const float*)d_in[0];
    const float* W1  = (const float*)d_in[1];
    const float* W2  = (const float*)d_in[2];
    const float* Wo1 = (const float*)d_in[3];
    const float* bo1 = (const float*)d_in[4];
    const float* Wo2 = (const float*)d_in[5];
    const float* bo2 = (const float*)d_in[6];
    float* outp = (float*)d_out;

    const int B = in_sizes[0] / NPAIR;   // 4096
    gcn_fused<<<B, 256, 0, stream>>>(coh, W1, W2, Wo1, bo1, Wo2, bo2, outp);
}